// Round 5
// baseline (167.235 us; speedup 1.0000x reference)
//
#include <hip/hip_runtime.h>
#include <math.h>

#define NPAIR 31
#define NBLK  130   // 2 norm + 128 psi

typedef __attribute__((ext_vector_type(8))) short bf8_t;   // 8 x bf16
typedef __attribute__((ext_vector_type(4))) float f4_t;    // 4 x fp32

#define MFMA(a, b, c) __builtin_amdgcn_mfma_f32_16x16x32_bf16((a), (b), (c), 0, 0, 0)
// barrier that drains only LDS ops — prefetch global loads stay in flight
#define LGKM_BARRIER() asm volatile("s_waitcnt lgkmcnt(0)\n\ts_barrier" ::: "memory")

__device__ __forceinline__ unsigned short f2bf(float f) {
    unsigned int u = __float_as_uint(f);
    return (unsigned short)((u + 0x7FFFu + ((u >> 16) & 1u)) >> 16);
}
__device__ __forceinline__ float bf2f(unsigned short h) {
    return __uint_as_float(((unsigned int)h) << 16);
}

// ---- ws layout ----
// floats: [0]=psisum [1]=lsf [2]=lsb ; int [3]=completion counter
// E_fwd fp32[4096] at float 1024 ; E_bwd at float 6144
// bytes: PBT (pair products, column-major rows, swizzled) at 45056 (31*4*8KB)
//        PMR (pair products, row-major, swizzled)          at 1060864
#define WS_E_OFF 1024
#define WS_B_OFF 6144
#define WS_PBT   45056
#define WS_PMR   1060864
// swizzled tile element (row n, col k): n*64 + (((k>>3)^(n&7))<<3) + (k&7)

// ---------- precompute pair products P = M_{2t}[a] @ M_{2t+1}[b], c = a + 2b ----------
extern "C" __global__ __launch_bounds__(256)
void mps_pre(const float* __restrict__ bulkG, unsigned short* __restrict__ PBTg,
             unsigned short* __restrict__ PMRg, float* __restrict__ wsF)
{
    extern __shared__ char smem[];
    unsigned short* S = (unsigned short*)smem;   // 32768 ush = 64 KB
    const int t = blockIdx.x, tid = threadIdx.x;
    const int wv = tid >> 6, lane = tid & 63, quad = lane >> 4, ln = lane & 15;
    if (t == 0 && tid == 0) { wsF[0] = 0.f; wsF[1] = 0.f; wsF[2] = 0.f; ((int*)wsF)[3] = 0; }

    unsigned short* Arow = S;          // site 2t, row-major swz, 2 branches
    unsigned short* Bbt  = S + 8192;   // site 2t+1, transposed swz, 2 branches
    const float4* sA = (const float4*)(bulkG + (size_t)(2 * t) * 8192);
    const float4* sB = (const float4*)(bulkG + (size_t)(2 * t + 1) * 8192);
    for (int it = 0; it < 8; ++it) {
        int idx = tid + it * 256;
        int f = idx * 4, kk = f >> 7, p = (f >> 6) & 1, j = f & 63;
        float4 va = sA[idx];
        ushort4 pa; pa.x = f2bf(va.x); pa.y = f2bf(va.y); pa.z = f2bf(va.z); pa.w = f2bf(va.w);
        *(ushort4*)(Arow + p * 4096 + kk * 64 + (((j >> 3) ^ (kk & 7)) << 3) + (j & 7)) = pa;
        float4 vb = sB[idx];
        unsigned short bb[4] = {f2bf(vb.x), f2bf(vb.y), f2bf(vb.z), f2bf(vb.w)};
        #pragma unroll
        for (int r2 = 0; r2 < 4; ++r2) {
            int n = j + r2;
            Bbt[p * 4096 + n * 64 + (((kk >> 3) ^ (n & 7)) << 3) + (kk & 7)] = bb[r2];
        }
    }
    __syncthreads();
    const int a = wv & 1, b = wv >> 1;
    bf8_t Af[4][2], Bf[4][2];
    #pragma unroll
    for (int mt = 0; mt < 4; ++mt)
        #pragma unroll
        for (int h = 0; h < 2; ++h) {
            Af[mt][h] = *(const bf8_t*)(Arow + a * 4096 + (mt * 16 + ln) * 64 + (((h * 4 + quad) ^ (ln & 7)) << 3));
            Bf[mt][h] = *(const bf8_t*)(Bbt  + b * 4096 + (mt * 16 + ln) * 64 + (((h * 4 + quad) ^ (ln & 7)) << 3));
        }
    __syncthreads();   // all frag reads landed; S reusable
    f4_t acc[4][4];
    #pragma unroll
    for (int mt = 0; mt < 4; ++mt)
        #pragma unroll
        for (int nt = 0; nt < 4; ++nt) {
            f4_t x = {0.f, 0.f, 0.f, 0.f};
            x = MFMA(Af[mt][0], Bf[nt][0], x);
            x = MFMA(Af[mt][1], Bf[nt][1], x);
            acc[mt][nt] = x;
        }
    unsigned short* Pr = S;            // row-major swz, 4 combos
    unsigned short* Pt = S + 16384;    // transposed swz, 4 combos
    #pragma unroll
    for (int mt = 0; mt < 4; ++mt)
        #pragma unroll
        for (int nt = 0; nt < 4; ++nt)
            #pragma unroll
            for (int r = 0; r < 4; ++r) {
                int row = mt * 16 + quad * 4 + r, col = nt * 16 + ln;
                unsigned short v = f2bf(acc[mt][nt][r]);
                Pr[wv * 4096 + row * 64 + (((col >> 3) ^ (row & 7)) << 3) + (col & 7)] = v;
                Pt[wv * 4096 + col * 64 + (((row >> 3) ^ (col & 7)) << 3) + (row & 7)] = v;
            }
    __syncthreads();
    const uint4* pr4 = (const uint4*)Pr;
    const uint4* pt4 = (const uint4*)Pt;
    uint4* mr = (uint4*)(PMRg + (size_t)t * 16384);
    uint4* bt = (uint4*)(PBTg + (size_t)t * 16384);
    for (int it = 0; it < 8; ++it) {
        int idx = tid + it * 256;
        mr[idx] = pr4[idx];
        bt[idx] = pt4[idx];
    }
}

// ---------- main: 2 norm blocks + 128 psi blocks, fused finalize ----------
extern "C" __global__ __launch_bounds__(256, 1)
void mps_main(const int* __restrict__ cfgG, const float* __restrict__ leftG,
              const float* __restrict__ rightG, float* __restrict__ wsF,
              const unsigned short* __restrict__ PBTg,
              const unsigned short* __restrict__ PMRg,
              float* __restrict__ outG)
{
    extern __shared__ char smem[];
    unsigned short* smem16 = (unsigned short*)smem;
    const int tid  = threadIdx.x;
    const int bid  = blockIdx.x;
    const int wv   = tid >> 6;
    const int lane = tid & 63;
    const int quad = lane >> 4;
    const int ln   = lane & 15;

    if (bid >= 2) {
        // ===== psi: 64 samples/block; 31 pair-steps; lgkm-only barriers =====
        unsigned short* tile = smem16;                    // 16384 ush (32 KB, swizzled)
        unsigned short* env  = tile + 16384;              // 4096 ush (swizzled, no pad)
        unsigned char*  selT = (unsigned char*)(env + 4096);   // [col][sample] 64x64
        unsigned char*  selP = selT + 4096;               // [pair][sample] 31x64

        const int s0 = (bid - 2) * 64;
        {
            int m = tid >> 2, part = tid & 3;
            const int* row = cfgG + (size_t)(s0 + m) * 64 + part * 16;
            #pragma unroll
            for (int q = 0; q < 4; ++q) {
                int4 v = *(const int4*)(row + q * 4);
                int cb = part * 16 + q * 4;
                selT[(cb + 0) * 64 + m] = (unsigned char)v.x;
                selT[(cb + 1) * 64 + m] = (unsigned char)v.y;
                selT[(cb + 2) * 64 + m] = (unsigned char)v.z;
                selT[(cb + 3) * 64 + m] = (unsigned char)v.w;
            }
        }
        __syncthreads();
        for (int idx = tid; idx < NPAIR * 64; idx += 256) {
            int pt2 = idx >> 6, m = idx & 63;
            selP[idx] = (unsigned char)(selT[(2 * pt2 + 1) * 64 + m] + 2 * selT[(2 * pt2 + 2) * 64 + m]);
        }
        bf8_t Af0, Af1;
        {
            int sel0 = selT[wv * 16 + ln];
            const float* lp0 = leftG + sel0 * 64;
            bf8_t t0, t1;
            #pragma unroll
            for (int j = 0; j < 8; ++j) {
                t0[j] = (short)f2bf(lp0[quad * 8 + j]);
                t1[j] = (short)f2bf(lp0[32 + quad * 8 + j]);
            }
            Af0 = t0; Af1 = t1;
        }
        uint4 pf[8];
        {
            const uint4* g0 = (const uint4*)PBTg;
            #pragma unroll
            for (int c = 0; c < 8; ++c)
                pf[c] = g0[(wv * 8 + c) * 64 + lane];
        }

        for (int t = 0; t < NPAIR; ++t) {
            LGKM_BARRIER();   // prev step's tile readers done; selP visible at t=0
            {
                uint4* tl4 = (uint4*)tile;
                #pragma unroll
                for (int c = 0; c < 8; ++c)
                    tl4[(wv * 8 + c) * 64 + lane] = pf[c];
            }
            LGKM_BARRIER();   // tile resident
            if (t + 1 < NPAIR) {
                const uint4* gn = (const uint4*)(PBTg + (size_t)(t + 1) * 16384);
                #pragma unroll
                for (int c = 0; c < 8; ++c)
                    pf[c] = gn[(wv * 8 + c) * 64 + lane];
            }
            f4_t acc[4][4];
            #pragma unroll
            for (int c = 0; c < 4; ++c)
                #pragma unroll
                for (int ct = 0; ct < 4; ++ct) {
                    const unsigned short* rb = tile + c * 4096 + (ct * 16 + ln) * 64;
                    bf8_t b0 = *(const bf8_t*)(rb + ((quad ^ (ln & 7)) << 3));
                    bf8_t b1 = *(const bf8_t*)(rb + (((4 + quad) ^ (ln & 7)) << 3));
                    f4_t x = {0.f, 0.f, 0.f, 0.f};
                    x = MFMA(Af0, b0, x);
                    x = MFMA(Af1, b1, x);
                    acc[c][ct] = x;
                }
            unsigned int sv = *(const unsigned int*)(selP + t * 64 + wv * 16 + quad * 4);
            #pragma unroll
            for (int ct = 0; ct < 4; ++ct)
                #pragma unroll
                for (int r = 0; r < 4; ++r) {
                    unsigned int bs = (sv >> (8 * r)) & 3u;
                    float v01 = (bs & 1u) ? acc[1][ct][r] : acc[0][ct][r];
                    float v23 = (bs & 1u) ? acc[3][ct][r] : acc[2][ct][r];
                    float v   = (bs & 2u) ? v23 : v01;
                    int row = wv * 16 + quad * 4 + r;
                    env[row * 64 + (((ct * 2 + (ln >> 3)) ^ (row & 7)) << 3) + (ln & 7)] = f2bf(v);
                }
            // same-wave DS ordering guarantees RAW on env
            Af0 = *(const bf8_t*)(env + (wv * 16 + ln) * 64 + ((quad ^ (ln & 7)) << 3));
            Af1 = *(const bf8_t*)(env + (wv * 16 + ln) * 64 + (((4 + quad) ^ (ln & 7)) << 3));
        }
        {   // psi = env . right[:, selL]
            int row = wv * 16 + ln;
            int selL = selT[63 * 64 + row];
            bf8_t e0 = *(const bf8_t*)(env + row * 64 + (((quad * 2) ^ (row & 7)) << 3));
            bf8_t e1 = *(const bf8_t*)(env + row * 64 + (((quad * 2 + 1) ^ (row & 7)) << 3));
            float p = 0.f;
            #pragma unroll
            for (int j = 0; j < 8; ++j)
                p = fmaf(bf2f((unsigned short)e0[j]), rightG[(quad * 16 + j) * 2 + selL], p);
            #pragma unroll
            for (int j = 0; j < 8; ++j)
                p = fmaf(bf2f((unsigned short)e1[j]), rightG[(quad * 16 + 8 + j) * 2 + selL], p);
            p += __shfl_xor(p, 16);
            p += __shfl_xor(p, 32);
            float lp = logf(fmaxf(p * p, 1e-12f));
            lp += __shfl_xor(lp, 1); lp += __shfl_xor(lp, 2);
            lp += __shfl_xor(lp, 4); lp += __shfl_xor(lp, 8);
            if (lane == 0) atomicAdd(&wsF[0], lp);
        }
    } else {
        // ===== norm chain: fwd (bid 0, pairs 0..15) / bwd (bid 1, pairs 30..16) =====
        unsigned short* Ebf = smem16;           // 4096 ush swizzled
        unsigned short* Sst = Ebf + 4096;       // 4 combos x 4096, transposed swz
        float* wred = (float*)(Sst + 16384);    // [2][4]

        const bool fwd = (bid == 0);
        const int NP = fwd ? 16 : 15;
        const unsigned short* srcbase = fwd ? PBTg : PMRg;
        {
            int i = tid >> 2, jq = tid & 3;
            for (int jj = 0; jj < 16; ++jj) {
                int j = jq * 16 + jj;
                float v;
                if (fwd) v = leftG[i] * leftG[j] + leftG[64 + i] * leftG[64 + j];
                else     v = rightG[i * 2] * rightG[j * 2] + rightG[i * 2 + 1] * rightG[j * 2 + 1];
                Ebf[i * 64 + (((j >> 3) ^ (i & 7)) << 3) + (j & 7)] = f2bf(v);
            }
        }
        float lsum = 0.f;
        const int mta = (wv >> 1) * 2;
        const int nta = (wv & 1) * 2;

        // lane-constant offsets
        int o1[4][2], o2[4][2][2];
        #pragma unroll
        for (int nt = 0; nt < 4; ++nt)
            #pragma unroll
            for (int h = 0; h < 2; ++h)
                o1[nt][h] = wv * 4096 + (nt * 16 + ln) * 64 + (((h * 4 + quad) ^ (ln & 7)) << 3);
        #pragma unroll
        for (int c = 0; c < 4; ++c)
            #pragma unroll
            for (int mi = 0; mi < 2; ++mi)
                #pragma unroll
                for (int h = 0; h < 2; ++h)
                    o2[c][mi][h] = c * 4096 + ((mta + mi) * 16 + ln) * 64 + (((h * 4 + quad) ^ (ln & 7)) << 3);

        bf8_t Bc0[4][2], Bc1[4][2];   // stage1 B frags, double-buffered
        {
            const unsigned short* base = srcbase + (size_t)(fwd ? 0 : 30) * 16384;
            #pragma unroll
            for (int nt = 0; nt < 4; ++nt)
                #pragma unroll
                for (int h = 0; h < 2; ++h)
                    Bc0[nt][h] = *(const bf8_t*)(base + o1[nt][h]);
        }

        for (int k = 0; k < NP; ++k) {
            LGKM_BARRIER();   // Ebf/wred(k-1) visible; Sst(k-1) readers done
            float inv = 1.f;
            if (k > 0) {
                const float* wp = wred + ((k - 1) & 1) * 4;
                float mm = fmaxf(fmaxf(wp[0], wp[1]), fmaxf(wp[2], wp[3]));
                float sc = fmaxf(mm, 1e-30f);
                inv = 1.f / sc;
                if (tid == 0) lsum += logf(sc);
            }
            // stage2 A-frags for current step (used ~600cy later)
            bf8_t Aw[4][2][2];
            {
                const unsigned short* base = srcbase + (size_t)(fwd ? k : (30 - k)) * 16384;
                #pragma unroll
                for (int c = 0; c < 4; ++c)
                    #pragma unroll
                    for (int mi = 0; mi < 2; ++mi)
                        #pragma unroll
                        for (int h = 0; h < 2; ++h)
                            Aw[c][mi][h] = *(const bf8_t*)(base + o2[c][mi][h]);
            }
            // stage1 B-frags for next step
            bf8_t (&Bcur)[4][2] = (k & 1) ? Bc1 : Bc0;
            if (k + 1 < NP) {
                bf8_t (&Bnxt)[4][2] = (k & 1) ? Bc0 : Bc1;
                const unsigned short* base = srcbase + (size_t)(fwd ? (k + 1) : (30 - (k + 1))) * 16384;
                #pragma unroll
                for (int nt = 0; nt < 4; ++nt)
                    #pragma unroll
                    for (int h = 0; h < 2; ++h)
                        Bnxt[nt][h] = *(const bf8_t*)(base + o1[nt][h]);
            }
            // stage1: S_c = E @ P_c  (combo c = wv), stored transposed+swizzled
            {
                unsigned short* SstW = Sst + wv * 4096;
                #pragma unroll
                for (int mt = 0; mt < 4; ++mt) {
                    const unsigned short* er = Ebf + (mt * 16 + ln) * 64;
                    bf8_t a0 = *(const bf8_t*)(er + ((quad ^ (ln & 7)) << 3));
                    bf8_t a1 = *(const bf8_t*)(er + (((4 + quad) ^ (ln & 7)) << 3));
                    #pragma unroll
                    for (int nt = 0; nt < 4; ++nt) {
                        f4_t x = {0.f, 0.f, 0.f, 0.f};
                        x = MFMA(a0, Bcur[nt][0], x);
                        x = MFMA(a1, Bcur[nt][1], x);
                        int n = nt * 16 + ln;
                        int dg = mt * 2 + (quad >> 1);
                        ushort4 pk;
                        pk.x = f2bf(x[0]); pk.y = f2bf(x[1]); pk.z = f2bf(x[2]); pk.w = f2bf(x[3]);
                        *(ushort4*)(SstW + n * 64 + ((dg ^ (n & 7)) << 3) + (quad & 1) * 4) = pk;
                    }
                }
            }
            LGKM_BARRIER();   // Sst resident
            // stage2: E' = sum_c P_c^T S_c  (2x2 output tiles per wave)
            {
                bf8_t Bw[4][2][2];
                #pragma unroll
                for (int c = 0; c < 4; ++c)
                    #pragma unroll
                    for (int ni = 0; ni < 2; ++ni)
                        #pragma unroll
                        for (int h = 0; h < 2; ++h)
                            Bw[c][ni][h] = *(const bf8_t*)(Sst + c * 4096 + ((nta + ni) * 16 + ln) * 64
                                                           + (((h * 4 + quad) ^ (ln & 7)) << 3));
                float mx = 0.f;
                #pragma unroll
                for (int mi = 0; mi < 2; ++mi)
                    #pragma unroll
                    for (int ni = 0; ni < 2; ++ni) {
                        f4_t x = {0.f, 0.f, 0.f, 0.f};
                        #pragma unroll
                        for (int c = 0; c < 4; ++c) {
                            x = MFMA(Aw[c][mi][0], Bw[c][ni][0], x);
                            x = MFMA(Aw[c][mi][1], Bw[c][ni][1], x);
                        }
                        #pragma unroll
                        for (int r = 0; r < 4; ++r) {
                            float val = x[r] * inv;
                            mx = fmaxf(mx, fabsf(val));
                            int row = (mta + mi) * 16 + quad * 4 + r;
                            int col = (nta + ni) * 16 + ln;
                            Ebf[row * 64 + (((col >> 3) ^ (row & 7)) << 3) + (col & 7)] = f2bf(val);
                        }
                    }
                #pragma unroll
                for (int off = 32; off > 0; off >>= 1)
                    mx = fmaxf(mx, __shfl_xor(mx, off));
                if (lane == 0) wred[(k & 1) * 4 + wv] = mx;
            }
        }
        __syncthreads();
        float* dst = wsF + (fwd ? WS_E_OFF : WS_B_OFF);
        for (int c = 0; c < 16; ++c) {
            int idx = tid + c * 256;
            int i = idx >> 6, j = idx & 63;
            dst[idx] = bf2f(Ebf[i * 64 + (((j >> 3) ^ (i & 7)) << 3) + (j & 7)]);
        }
        if (tid == 0) wsF[fwd ? 1 : 2] = lsum;
    }

    // ===== fused finalize: last block computes the output =====
    __syncthreads();
    __threadfence();
    __syncthreads();
    int* eflag = (int*)smem;
    if (tid == 0) {
        int old = atomicAdd((int*)wsF + 3, 1);
        eflag[0] = (old == NBLK - 1) ? 1 : 0;
    }
    __syncthreads();
    if (eflag[0]) {
        __threadfence();
        const float4* E  = (const float4*)(wsF + WS_E_OFF);
        const float4* Bm = (const float4*)(wsF + WS_B_OFF);
        float a = 0.f;
        #pragma unroll
        for (int c = 0; c < 4; ++c) {
            int idx = tid + c * 256;
            float4 e = E[idx], b = Bm[idx];
            a += e.x * b.x + e.y * b.y + e.z * b.z + e.w * b.w;
        }
        #pragma unroll
        for (int off = 32; off > 0; off >>= 1)
            a += __shfl_down(a, off);
        float* ered = (float*)smem + 8;
        if ((tid & 63) == 0) ered[tid >> 6] = a;
        __syncthreads();
        if (tid == 0) {
            float z = fmaxf(ered[0] + ered[1] + ered[2] + ered[3], 1e-30f);
            float log_z = logf(z) + wsF[1] + wsF[2];
            outG[0] = log_z - wsF[0] * (1.0f / 8192.0f);
        }
    }
}

extern "C" void kernel_launch(void* const* d_in, const int* in_sizes, int n_in,
                              void* d_out, int out_size, void* d_ws, size_t ws_size,
                              hipStream_t stream)
{
    const int*   cfg   = (const int*)d_in[0];    // (8192, 64) int32
    const float* left  = (const float*)d_in[1];  // (2, 64)
    const float* bulk  = (const float*)d_in[2];  // (62, 64, 2, 64)
    const float* right = (const float*)d_in[3];  // (64, 2)
    float* wsF = (float*)d_ws;
    unsigned short* PBTg = (unsigned short*)((char*)d_ws + WS_PBT);
    unsigned short* PMRg = (unsigned short*)((char*)d_ws + WS_PMR);

    mps_pre<<<dim3(NPAIR), dim3(256), 65536, stream>>>(bulk, PBTg, PMRg, wsF);
    mps_main<<<dim3(NBLK), dim3(256), 47104, stream>>>(cfg, left, right, wsF, PBTg, PMRg, (float*)d_out);
}

// Round 7
// 120.507 us; speedup vs baseline: 1.3878x; 1.3878x over previous
//
#include <hip/hip_runtime.h>
#include <math.h>

#define NBULK 62
#define NBLK  130   // 2 norm + 128 psi

typedef __attribute__((ext_vector_type(8))) short bf8_t;   // 8 x bf16
typedef __attribute__((ext_vector_type(4))) float f4_t;    // 4 x fp32

#define MFMA(a, b, c) __builtin_amdgcn_mfma_f32_16x16x32_bf16((a), (b), (c), 0, 0, 0)
// barrier that drains only LDS ops — global prefetches stay in flight
#define LGKM_BARRIER() asm volatile("s_waitcnt lgkmcnt(0)\n\ts_barrier" ::: "memory")

__device__ __forceinline__ unsigned short f2bf(float f) {
    unsigned int u = __float_as_uint(f);
    return (unsigned short)((u + 0x7FFFu + ((u >> 16) & 1u)) >> 16);
}
__device__ __forceinline__ float bf2f(unsigned short h) {
    return __uint_as_float(((unsigned int)h) << 16);
}
__device__ __forceinline__ void gload16(const void* g, void* l) {
    __builtin_amdgcn_global_load_lds(
        (const __attribute__((address_space(1))) unsigned int*)g,
        (__attribute__((address_space(3))) unsigned int*)l, 16, 0, 0);
}

// ---- ws layout ----
// floats: [0]=psisum [1]=lsf [2]=lsb ; int [3]=completion counter
// E_fwd fp32[4096] at float 1024 ; E_bwd at float 6144
// bytes: BT (62*16KB, swizzled) at 45056 ; MR at 1060864
#define WS_E_OFF   1024
#define WS_B_OFF   6144
#define WS_BT_OFF  45056
#define WS_MR_OFF  1060864
// swizzled tile element (row n, col k): n*64 + ((k>>3 ^ (n&7))<<3 | (k&7))

extern "C" __global__ __launch_bounds__(256)
void mps_precompute(const float* __restrict__ bulkG,
                    unsigned short* __restrict__ BTg,
                    unsigned short* __restrict__ MRg,
                    float* __restrict__ wsF)
{
    __shared__ unsigned short BTl[8192];
    __shared__ unsigned short MRl[8192];
    const int s = blockIdx.x, tid = threadIdx.x;
    if (s == 0 && tid == 0) {
        wsF[0] = 0.f; wsF[1] = 0.f; wsF[2] = 0.f;
        ((int*)wsF)[3] = 0;
    }
    const float4* src = (const float4*)(bulkG + (size_t)s * 8192);
    for (int c = 0; c < 8; ++c) {
        int idx = tid + c * 256;
        float4 v = src[idx];
        int f  = idx * 4;
        int kk = f >> 7;
        int p  = (f >> 6) & 1;
        int j  = f & 63;
        unsigned short b0 = f2bf(v.x), b1 = f2bf(v.y), b2 = f2bf(v.z), b3 = f2bf(v.w);
        int n = p * 64 + kk;
        int off = n * 64 + (((j >> 3) ^ (n & 7)) << 3) + (j & 7);
        MRl[off + 0] = b0; MRl[off + 1] = b1; MRl[off + 2] = b2; MRl[off + 3] = b3;
        unsigned short bb[4] = {b0, b1, b2, b3};
        #pragma unroll
        for (int t2 = 0; t2 < 4; ++t2) {
            int n2 = p * 64 + j + t2;
            BTl[n2 * 64 + (((kk >> 3) ^ (n2 & 7)) << 3) + (kk & 7)] = bb[t2];
        }
    }
    __syncthreads();
    const uint4* bt4 = (const uint4*)BTl;
    const uint4* mr4 = (const uint4*)MRl;
    uint4* btg = (uint4*)(BTg + (size_t)s * 8192);
    uint4* mrg = (uint4*)(MRg + (size_t)s * 8192);
    for (int c = 0; c < 4; ++c) {
        int idx = tid + c * 256;
        btg[idx] = bt4[idx];
        mrg[idx] = mr4[idx];
    }
}

extern "C" __global__ __launch_bounds__(256, 1)
void mps_main(const int* __restrict__ cfgG, const float* __restrict__ leftG,
              const float* __restrict__ rightG, float* __restrict__ wsF,
              const unsigned short* __restrict__ BTg,
              const unsigned short* __restrict__ MRg,
              float* __restrict__ outG)
{
    extern __shared__ char smem[];
    unsigned short* smem16 = (unsigned short*)smem;
    const int tid  = threadIdx.x;
    const int bid  = blockIdx.x;
    const int wv   = tid >> 6;
    const int lane = tid & 63;
    const int quad = lane >> 4;
    const int ln   = lane & 15;
    const int swz  = ln & 7;

    if (bid >= 2) {
        // ===== psi (transposed orientation): lane's sample = wv*16+ln =====
        unsigned short* Tb0 = smem16;          // 8192 ush tile
        unsigned short* Tb1 = Tb0 + 8192;
        unsigned short* env = Tb1 + 8192;      // env[s][k] swizzled by s&7

        const int s0  = (bid - 2) * 64;
        const int sMy = wv * 16 + ln;
        const int esw = (sMy & 7) << 3;
        unsigned short* eb = env + sMy * 64;

        // pack this sample's 64 config bits into a register mask
        unsigned long long SEL = 0ull;
        {
            const int* row = cfgG + (size_t)(s0 + sMy) * 64;
            #pragma unroll
            for (int q = 0; q < 16; ++q) {
                int4 v = *(const int4*)(row + q * 4);
                SEL |= ((unsigned long long)(v.x & 1)) << (q * 4);
                SEL |= ((unsigned long long)(v.y & 1)) << (q * 4 + 1);
                SEL |= ((unsigned long long)(v.z & 1)) << (q * 4 + 2);
                SEL |= ((unsigned long long)(v.w & 1)) << (q * 4 + 3);
            }
        }
        {   // prefetch tile 0
            const char* g0 = (const char*)BTg;
            for (int c = 0; c < 4; ++c) {
                int chunk = wv * 4 + c;
                gload16(g0 + chunk * 1024 + (size_t)lane * 16, (char*)Tb0 + chunk * 1024);
            }
        }
        bf8_t Ef0, Ef1;   // env-frags (B-operand layout: n=ln=sample, k=quad*8+j)
        {
            int sel0 = (int)(SEL & 1ull);
            const float* lp = leftG + sel0 * 64;
            bf8_t t0, t1;
            #pragma unroll
            for (int j = 0; j < 8; ++j) {
                t0[j] = (short)f2bf(lp[quad * 8 + j]);
                t1[j] = (short)f2bf(lp[32 + quad * 8 + j]);
            }
            Ef0 = t0; Ef1 = t1;
        }

        for (int t = 0; t < NBULK; ++t) {
            __syncthreads();   // tile t resident (prefetch issued a full site ago)
            unsigned short* Tl = (t & 1) ? Tb1 : Tb0;
            if (t + 1 < NBULK) {
                const char* gn = (const char*)(BTg + (size_t)(t + 1) * 8192);
                char* l = (char*)((t & 1) ? Tb0 : Tb1);
                for (int c = 0; c < 4; ++c) {
                    int chunk = wv * 4 + c;
                    gload16(gn + chunk * 1024 + (size_t)lane * 16, l + chunk * 1024);
                }
            }
            // env'(out,sample) = M^T env^T : A = BT rows (out), B = env-frags
            f4_t a0[4], a1[4];
            #pragma unroll
            for (int mt = 0; mt < 4; ++mt) {
                const unsigned short* r0 = Tl + (mt * 16 + ln) * 64;
                const unsigned short* r1 = Tl + (64 + mt * 16 + ln) * 64;
                bf8_t A00 = *(const bf8_t*)(r0 + ((quad       ^ swz) << 3));
                bf8_t A01 = *(const bf8_t*)(r0 + (((4 + quad) ^ swz) << 3));
                bf8_t A10 = *(const bf8_t*)(r1 + ((quad       ^ swz) << 3));
                bf8_t A11 = *(const bf8_t*)(r1 + (((4 + quad) ^ swz) << 3));
                f4_t x = {0.f, 0.f, 0.f, 0.f};
                x = MFMA(A00, Ef0, x);
                x = MFMA(A01, Ef1, x);
                a0[mt] = x;
                f4_t y = {0.f, 0.f, 0.f, 0.f};
                y = MFMA(A10, Ef0, y);
                y = MFMA(A11, Ef1, y);
                a1[mt] = y;
            }
            const bool bs = ((SEL >> (t + 1)) & 1ull) != 0ull;
            #pragma unroll
            for (int mt = 0; mt < 4; ++mt) {
                ushort4 pk;
                pk.x = f2bf(bs ? a1[mt][0] : a0[mt][0]);
                pk.y = f2bf(bs ? a1[mt][1] : a0[mt][1]);
                pk.z = f2bf(bs ? a1[mt][2] : a0[mt][2]);
                pk.w = f2bf(bs ? a1[mt][3] : a0[mt][3]);
                *(ushort4*)(eb + ((mt * 16 + quad * 4) ^ esw)) = pk;
            }
            // reload env-frags (same-wave DS ordering guarantees RAW)
            Ef0 = *(const bf8_t*)(eb + ((quad * 8)      ^ esw));
            Ef1 = *(const bf8_t*)(eb + ((quad * 8 + 32) ^ esw));
        }
        {   // psi epilogue: quad-partial dot product, then quad-sum — each sample counted ONCE
            const int selL = (int)((SEL >> 63) & 1ull);
            float p = 0.f;
            #pragma unroll
            for (int g2 = 0; g2 < 2; ++g2) {
                int g = quad * 2 + g2;                  // this quad's 2 k-groups
                bf8_t e = *(const bf8_t*)(eb + ((g * 8) ^ esw));
                #pragma unroll
                for (int j = 0; j < 8; ++j)
                    p = fmaf(bf2f((unsigned short)e[j]), rightG[(g * 8 + j) * 2 + selL], p);
            }
            p += __shfl_xor(p, 16);   // sum the 4 quads -> full psi in every lane
            p += __shfl_xor(p, 32);
            float lp = logf(fmaxf(p * p, 1e-12f));
            lp += __shfl_xor(lp, 1); lp += __shfl_xor(lp, 2);    // sum 16 distinct samples
            lp += __shfl_xor(lp, 4); lp += __shfl_xor(lp, 8);
            if (lane == 0) atomicAdd(&wsF[0], lp);
        }
    } else {
        // ===== norm chain (E symmetric): fwd (bid 0) / bwd (bid 1), 31 sites =====
        unsigned short* Tb0 = smem16;          // 8192
        unsigned short* Tb1 = Tb0 + 8192;
        unsigned short* E   = Tb1 + 8192;      // 4096 ush, E[i][j] swz by i&7
        unsigned short* St  = E + 4096;        // 2 x 4096: St_p[n][i] swz by n&7
        float* wred = (float*)(St + 8192);     // [2][4]

        const bool fwd = (bid == 0);
        const unsigned short* srcbase = fwd ? BTg : MRg;
        {   // E0 (symmetric)
            int i = tid >> 2, jq = tid & 3;
            for (int jj = 0; jj < 16; ++jj) {
                int j = jq * 16 + jj;
                float v;
                if (fwd) v = leftG[i] * leftG[j] + leftG[64 + i] * leftG[64 + j];
                else     v = rightG[i * 2] * rightG[j * 2] + rightG[i * 2 + 1] * rightG[j * 2 + 1];
                E[i * 64 + (j ^ ((i & 7) << 3))] = f2bf(v);
            }
        }
        {   // prefetch site 0
            int st = fwd ? 0 : 61;
            const char* g = (const char*)(srcbase + (size_t)st * 8192);
            for (int c = 0; c < 4; ++c) {
                int chunk = wv * 4 + c;
                gload16(g + chunk * 1024 + (size_t)lane * 16, (char*)Tb0 + chunk * 1024);
            }
        }
        float lsum = 0.f;
        const int p   = wv >> 1;          // stage1 branch
        const int ntb = (wv & 1) * 2;     // stage1 n-tile pair
        const int mta = (wv >> 1) * 2;    // stage2 quadrant
        const int nta = (wv & 1) * 2;

        for (int k = 0; k < 31; ++k) {
            __syncthreads();   // tile k resident; E(k-1)/wred(k-1) visible
            unsigned short* Tl = (k & 1) ? Tb1 : Tb0;
            if (k + 1 < 31) {
                int sn = fwd ? (k + 1) : (61 - (k + 1));
                const char* g = (const char*)(srcbase + (size_t)sn * 8192);
                char* l = (char*)((k & 1) ? Tb0 : Tb1);
                for (int c = 0; c < 4; ++c) {
                    int chunk = wv * 4 + c;
                    gload16(g + chunk * 1024 + (size_t)lane * 16, l + chunk * 1024);
                }
            }
            float inv = 1.f;
            if (k > 0) {
                const float* wp = wred + ((k - 1) & 1) * 4;
                float mm = fmaxf(fmaxf(wp[0], wp[1]), fmaxf(wp[2], wp[3]));
                float sc = fmaxf(mm, 1e-30f);
                inv = 1.f / sc;
                if (tid == 0) lsum += logf(sc);
            }
            // stage1: S_p = E @ M_p ; store St_p[n][i] (i-contig, b64 packs)
            {
                bf8_t Bf[2][2];
                #pragma unroll
                for (int c = 0; c < 2; ++c) {
                    const unsigned short* rb = Tl + (p * 64 + (ntb + c) * 16 + ln) * 64;
                    Bf[c][0] = *(const bf8_t*)(rb + ((quad       ^ swz) << 3));
                    Bf[c][1] = *(const bf8_t*)(rb + (((4 + quad) ^ swz) << 3));
                }
                #pragma unroll
                for (int it = 0; it < 4; ++it) {
                    const unsigned short* er = E + (it * 16 + ln) * 64;
                    bf8_t A0 = *(const bf8_t*)(er + ((quad * 8)      ^ (swz << 3)));
                    bf8_t A1 = *(const bf8_t*)(er + ((quad * 8 + 32) ^ (swz << 3)));
                    #pragma unroll
                    for (int c = 0; c < 2; ++c) {
                        f4_t x = {0.f, 0.f, 0.f, 0.f};
                        x = MFMA(A0, Bf[c][0], x);
                        x = MFMA(A1, Bf[c][1], x);
                        int n = (ntb + c) * 16 + ln;
                        ushort4 pk;
                        pk.x = f2bf(x[0]); pk.y = f2bf(x[1]); pk.z = f2bf(x[2]); pk.w = f2bf(x[3]);
                        *(ushort4*)(St + p * 4096 + n * 64 + ((it * 16 + quad * 4) ^ ((n & 7) << 3))) = pk;
                    }
                }
            }
            LGKM_BARRIER();   // St resident (DS-only drain; prefetch stays in flight)
            // stage2: E' = sum_p M_p^T S_p ; write transposed (E symmetric), b64 packs
            {
                f4_t o[2][2];
                #pragma unroll
                for (int mi = 0; mi < 2; ++mi)
                    #pragma unroll
                    for (int ni = 0; ni < 2; ++ni) {
                        f4_t x = {0.f, 0.f, 0.f, 0.f};
                        #pragma unroll
                        for (int pp = 0; pp < 2; ++pp) {
                            const unsigned short* ar = Tl + (pp * 64 + (mta + mi) * 16 + ln) * 64;
                            bf8_t A0 = *(const bf8_t*)(ar + ((quad       ^ swz) << 3));
                            bf8_t A1 = *(const bf8_t*)(ar + (((4 + quad) ^ swz) << 3));
                            int n2 = (nta + ni) * 16 + ln;
                            const unsigned short* br = St + pp * 4096 + n2 * 64;
                            bf8_t B0 = *(const bf8_t*)(br + ((quad * 8)      ^ ((n2 & 7) << 3)));
                            bf8_t B1 = *(const bf8_t*)(br + ((quad * 8 + 32) ^ ((n2 & 7) << 3)));
                            x = MFMA(A0, B0, x);
                            x = MFMA(A1, B1, x);
                        }
                        o[mi][ni] = x;
                    }
                float mx = 0.f;
                #pragma unroll
                for (int mi = 0; mi < 2; ++mi)
                    #pragma unroll
                    for (int ni = 0; ni < 2; ++ni) {
                        float v0 = o[mi][ni][0] * inv, v1 = o[mi][ni][1] * inv;
                        float v2 = o[mi][ni][2] * inv, v3 = o[mi][ni][3] * inv;
                        mx = fmaxf(mx, fmaxf(fmaxf(fabsf(v0), fabsf(v1)), fmaxf(fabsf(v2), fabsf(v3))));
                        ushort4 pk;
                        pk.x = f2bf(v0); pk.y = f2bf(v1); pk.z = f2bf(v2); pk.w = f2bf(v3);
                        int n2 = (nta + ni) * 16 + ln;
                        *(ushort4*)(E + n2 * 64 + (((mta + mi) * 16 + quad * 4) ^ ((n2 & 7) << 3))) = pk;
                    }
                mx = fmaxf(mx, __shfl_xor(mx, 1));  mx = fmaxf(mx, __shfl_xor(mx, 2));
                mx = fmaxf(mx, __shfl_xor(mx, 4));  mx = fmaxf(mx, __shfl_xor(mx, 8));
                mx = fmaxf(mx, __shfl_xor(mx, 16)); mx = fmaxf(mx, __shfl_xor(mx, 32));
                if (lane == 0) wred[(k & 1) * 4 + wv] = mx;
            }
        }
        __syncthreads();
        float* dst = wsF + (fwd ? WS_E_OFF : WS_B_OFF);
        for (int c = 0; c < 16; ++c) {
            int idx = tid + c * 256;
            int i = idx >> 6, j = idx & 63;
            dst[idx] = bf2f(E[i * 64 + (j ^ ((i & 7) << 3))]);
        }
        if (tid == 0) wsF[fwd ? 1 : 2] = lsum;
    }

    // ===== fused finalize: last block computes the output =====
    __syncthreads();
    __threadfence();
    __syncthreads();
    int* eflag = (int*)smem;
    if (tid == 0) {
        int old = atomicAdd((int*)wsF + 3, 1);
        eflag[0] = (old == NBLK - 1) ? 1 : 0;
    }
    __syncthreads();
    if (eflag[0]) {
        __threadfence();
        const float4* Ew = (const float4*)(wsF + WS_E_OFF);
        const float4* Bw = (const float4*)(wsF + WS_B_OFF);
        float a = 0.f;
        #pragma unroll
        for (int c = 0; c < 4; ++c) {
            int idx = tid + c * 256;
            float4 e = Ew[idx], b = Bw[idx];
            a += e.x * b.x + e.y * b.y + e.z * b.z + e.w * b.w;
        }
        #pragma unroll
        for (int off = 32; off > 0; off >>= 1)
            a += __shfl_down(a, off);
        float* ered = (float*)smem + 8;
        if ((tid & 63) == 0) ered[tid >> 6] = a;
        __syncthreads();
        if (tid == 0) {
            float z = fmaxf(ered[0] + ered[1] + ered[2] + ered[3], 1e-30f);
            float log_z = logf(z) + wsF[1] + wsF[2];
            outG[0] = log_z - wsF[0] * (1.0f / 8192.0f);
        }
    }
}

extern "C" void kernel_launch(void* const* d_in, const int* in_sizes, int n_in,
                              void* d_out, int out_size, void* d_ws, size_t ws_size,
                              hipStream_t stream)
{
    const int*   cfg   = (const int*)d_in[0];    // (8192, 64) int32
    const float* left  = (const float*)d_in[1];  // (2, 64)
    const float* bulk  = (const float*)d_in[2];  // (62, 64, 2, 64)
    const float* right = (const float*)d_in[3];  // (64, 2)
    float* wsF = (float*)d_ws;
    unsigned short* BTg = (unsigned short*)((char*)d_ws + WS_BT_OFF);
    unsigned short* MRg = (unsigned short*)((char*)d_ws + WS_MR_OFF);

    mps_precompute<<<dim3(62), dim3(256), 0, stream>>>(bulk, BTg, MRg, wsF);
    // blocks 0,1 = norm chains; 2..129 = psi (64 samples each); finalize fused
    mps_main<<<dim3(NBLK), dim3(256), 57472, stream>>>(cfg, left, right, wsF, BTg, MRg, (float*)d_out);
}